// Round 5
// baseline (140.724 us; speedup 1.0000x reference)
//
#include <hip/hip_runtime.h>

#define NN 768
#define IN_F 68
#define KNN 8
#define EO 32
#define FEAT 264
#define HALF_FEAT 132
#define EMB 32
#define NPAIR 294528   // 768*767/2

typedef __attribute__((ext_vector_type(8))) short bf16x8;
typedef __attribute__((ext_vector_type(4))) float f32x4;
typedef __attribute__((ext_vector_type(4))) unsigned short u16x4;

// pack hi16(x1):hi16(x0) into one dword — bf16 truncation of two floats, 1 v_perm
static __device__ __forceinline__ int pack_chop2(float x0, float x1) {
  return __builtin_amdgcn_perm(__float_as_uint(x1), __float_as_uint(x0), 0x07060302);
}
static __device__ __forceinline__ float chop(float x) {
  return __uint_as_float(__float_as_uint(x) & 0xffff0000u);
}
static __device__ __forceinline__ unsigned short bftrunc(float x) {
  return (unsigned short)(__float_as_uint(x) >> 16);
}
static __device__ __forceinline__ float lrelu(float x) { return fmaxf(x, 0.01f*x); }

#define MFMA(a,b,c) __builtin_amdgcn_mfma_f32_16x16x32_bf16((a),(b),(c),0,0,0)

// ---------------- Kernel A: top-8 (per-wave, stable) + EdgeConv1 as block GEMM ----
// block = 4 waves = 4 nodes. Phase 1: each wave does exact top-8 for its node
// (verified algorithm). Phase 2: gather 4x544 feats (k' = kn*68+c ordering,
// coalesced float4) -> split-bf16 LDS. Phase 3: [4x544]@[544x32] GEMM,
// k-chunks split across waves, LDS partial reduce. Phase 4: MLP2 via MFMA.
// w1 read once per block (26 MB total vs 104 MB per-wave).
__global__ void __launch_bounds__(256) topk_ec1_kernel(
    const float* __restrict__ feat0, const float* __restrict__ feat1,
    const float* __restrict__ w1, const float* __restrict__ b1,
    const float* __restrict__ w2, const float* __restrict__ b2,
    int* __restrict__ idx_out, float* __restrict__ e1out)
{
  const int bx = blockIdx.x, g = blockIdx.y;
  const float* __restrict__ feat = g ? feat1 : feat0;
  const int tid = threadIdx.x;
  const int lane = tid & 63, w = tid >> 6;
  const int i = bx*4 + w;

  __shared__ unsigned long long keys[4][512];
  __shared__ int nbr[4][8];
  __shared__ unsigned short Ahi[4][544], Alo[4][544];
  __shared__ float pbuf[4][4][32];
  __shared__ unsigned short h1hi[4][32], h1lo[4][32];

  // ---- phase 1: top-8, one wave per node ----
  const float4 ci = *(const float4*)(feat + i*IN_F);
  float4 cand[12];
#pragma unroll
  for (int t = 0; t < 12; t++)
    cand[t] = *(const float4*)(feat + (lane + 64*t)*IN_F);

  float bd[8]; int bidx[8];
#pragma unroll
  for (int k = 0; k < 8; k++) { bd[k] = 1e30f; bidx[k] = 0; }
#pragma unroll
  for (int t = 0; t < 12; t++) {
    const int j = lane + 64*t;
    float d = fabsf(ci.x - cand[t].x);   // same sequential add order as ref sum(-1)
    d += fabsf(ci.y - cand[t].y);
    d += fabsf(ci.z - cand[t].z);
    d += fabsf(ci.w - cand[t].w);
    if (d < bd[7]) {
#pragma unroll
      for (int k = 7; k >= 1; k--) {
        if (d < bd[k-1])    { bd[k] = bd[k-1]; bidx[k] = bidx[k-1]; }
        else if (d < bd[k]) { bd[k] = d;       bidx[k] = j; }
      }
      if (d < bd[0]) { bd[0] = d; bidx[0] = j; }
    }
  }
#pragma unroll
  for (int k = 0; k < 8; k++)
    keys[w][lane*8+k] = ((unsigned long long)__float_as_uint(bd[k]) << 32) | (unsigned)bidx[k];
  __syncthreads();
  int pos = 0;
#pragma unroll
  for (int r = 0; r < 8; r++) {
    unsigned long long mykey = keys[w][lane*8 + pos];
    unsigned long long mn = mykey;
#pragma unroll
    for (int s = 32; s >= 1; s >>= 1) {
      unsigned long long o = __shfl_xor(mn, s, 64);
      mn = (o < mn) ? o : mn;
    }
    if (mykey == mn) pos++;          // idx bits unique -> exactly one winner
    if (lane == 0) {
      int nb = (int)(mn & 0xffffffffull);
      nbr[w][r] = nb;
      idx_out[(g*NN+i)*8 + r] = nb;
    }
  }
  __syncthreads();

  // ---- phase 2: gather + split to bf16 (k' = kn*IN_F + c) ----
  for (int z = tid; z < 4*KNN*17; z += 256) {   // 544 float4 units
    int node = z / 136, rest = z - node*136;
    int kn = rest / 17, c4 = (rest - kn*17) * 4;
    float4 t = *(const float4*)(feat + nbr[node][kn]*IN_F + c4);
    int kidx = kn*IN_F + c4;
    u16x4 hi = { bftrunc(t.x), bftrunc(t.y), bftrunc(t.z), bftrunc(t.w) };
    u16x4 lo = { bftrunc(t.x - chop(t.x)), bftrunc(t.y - chop(t.y)),
                 bftrunc(t.z - chop(t.z)), bftrunc(t.w - chop(t.w)) };
    *(u16x4*)&Ahi[node][kidx] = hi;
    *(u16x4*)&Alo[node][kidx] = lo;
  }
  __syncthreads();

  // ---- phase 3: GEMM, 17 k-chunks split w, w+4, ... across waves ----
  const int q = lane & 15, kg = lane >> 4;
  f32x4 acc0 = {0.f,0.f,0.f,0.f}, acc1 = {0.f,0.f,0.f,0.f};
  for (int cc = w; cc < 17; cc += 4) {
    const int kb = cc*32 + kg*8;
    bf16x8 ah = *(const bf16x8*)&Ahi[q & 3][kb];
    bf16x8 al = *(const bf16x8*)&Alo[q & 3][kb];
    union { int i[4]; bf16x8 v; } bh0, bl0, bh1, bl1;
#pragma unroll
    for (int d = 0; d < 4; d++) {
      int k0 = kb + 2*d, k1 = k0 + 1;
      int r0 = (k0 % IN_F)*8 + (k0 / IN_F);   // w1 row for permuted k-ordering
      int r1 = (k1 % IN_F)*8 + (k1 / IN_F);
      float x0 = w1[r0*EO + q],      x1 = w1[r1*EO + q];
      float y0 = w1[r0*EO + 16 + q], y1 = w1[r1*EO + 16 + q];
      bh0.i[d] = pack_chop2(x0, x1);
      bl0.i[d] = pack_chop2(x0 - chop(x0), x1 - chop(x1));
      bh1.i[d] = pack_chop2(y0, y1);
      bl1.i[d] = pack_chop2(y0 - chop(y0), y1 - chop(y1));
    }
    acc0 = MFMA(ah, bh0.v, acc0); acc0 = MFMA(ah, bl0.v, acc0); acc0 = MFMA(al, bh0.v, acc0);
    acc1 = MFMA(ah, bh1.v, acc1); acc1 = MFMA(ah, bl1.v, acc1); acc1 = MFMA(al, bh1.v, acc1);
  }
  if (lane < 16) {   // rows 0..3 (the 4 real nodes) live in kg==0 lanes
#pragma unroll
    for (int r = 0; r < 4; r++) { pbuf[w][r][q] = acc0[r]; pbuf[w][r][16+q] = acc1[r]; }
  }
  __syncthreads();
  if (tid < 128) {
    int node = tid >> 5, n = tid & 31;
    float s = pbuf[0][node][n] + pbuf[1][node][n] + pbuf[2][node][n] + pbuf[3][node][n] + b1[n];
    s = lrelu(s);
    h1hi[node][n] = bftrunc(s);
    h1lo[node][n] = bftrunc(s - chop(s));
  }
  __syncthreads();

  // ---- phase 4: MLP2 [4x32]@[32x32]; all waves redundant, wave w writes node w
  {
    bf16x8 ah = *(const bf16x8*)&h1hi[q & 3][kg*8];
    bf16x8 al = *(const bf16x8*)&h1lo[q & 3][kg*8];
    union { int i[4]; bf16x8 v; } bh0, bl0, bh1, bl1;
#pragma unroll
    for (int d = 0; d < 4; d++) {
      int k0 = kg*8 + 2*d, k1 = k0 + 1;
      float x0 = w2[k0*EO + q],      x1 = w2[k1*EO + q];
      float y0 = w2[k0*EO + 16 + q], y1 = w2[k1*EO + 16 + q];
      bh0.i[d] = pack_chop2(x0, x1);
      bl0.i[d] = pack_chop2(x0 - chop(x0), x1 - chop(x1));
      bh1.i[d] = pack_chop2(y0, y1);
      bl1.i[d] = pack_chop2(y0 - chop(y0), y1 - chop(y1));
    }
    f32x4 c0 = {0.f,0.f,0.f,0.f}, c1 = {0.f,0.f,0.f,0.f};
    c0 = MFMA(ah, bh0.v, c0); c0 = MFMA(ah, bl0.v, c0); c0 = MFMA(al, bh0.v, c0);
    c1 = MFMA(ah, bh1.v, c1); c1 = MFMA(ah, bl1.v, c1); c1 = MFMA(al, bh1.v, c1);
    if (lane < 16) {
      float oA = lrelu(c0[w] + b2[q]);
      float oB = lrelu(c1[w] + b2[16+q]);
      e1out[(g*NN+i)*EO + q]      = oA;
      e1out[(g*NN+i)*EO + 16 + q] = oB;
    }
  }
}

// ---------------- Kernel B: EdgeConv2 as block GEMM (4 nodes/block) ----------------
__global__ void __launch_bounds__(256) ec2_kernel(
    const int* __restrict__ idx, const float* __restrict__ e1,
    const float* __restrict__ w1, const float* __restrict__ b1,
    const float* __restrict__ w2, const float* __restrict__ b2,
    float* __restrict__ e2out)
{
  const int bx = blockIdx.x, g = blockIdx.y;
  const int tid = threadIdx.x;
  const int lane = tid & 63, w = tid >> 6;
  const int i = bx*4 + w;

  __shared__ int nbrL[4][8];
  __shared__ unsigned short Ahi[4][256], Alo[4][256];
  __shared__ float pbuf[4][4][32];
  __shared__ unsigned short h1hi[4][32], h1lo[4][32];

  if (tid < 32) {
    int node = tid >> 3, kn = tid & 7;
    nbrL[node][kn] = idx[(g*NN + bx*4 + node)*8 + kn];
  }
  __syncthreads();

  // gather 4 x 256 (k' = kn*EO + c), coalesced float4
  {
    int z = tid;   // exactly 256 units
    int node = z >> 6, rest = z & 63;
    int kn = rest >> 3, c4 = (rest & 7) * 4;
    float4 t = *(const float4*)(e1 + (g*NN + nbrL[node][kn])*EO + c4);
    int kidx = kn*EO + c4;
    u16x4 hi = { bftrunc(t.x), bftrunc(t.y), bftrunc(t.z), bftrunc(t.w) };
    u16x4 lo = { bftrunc(t.x - chop(t.x)), bftrunc(t.y - chop(t.y)),
                 bftrunc(t.z - chop(t.z)), bftrunc(t.w - chop(t.w)) };
    *(u16x4*)&Ahi[node][kidx] = hi;
    *(u16x4*)&Alo[node][kidx] = lo;
  }
  __syncthreads();

  const int q = lane & 15, kg = lane >> 4;
  f32x4 acc0 = {0.f,0.f,0.f,0.f}, acc1 = {0.f,0.f,0.f,0.f};
  for (int cc = w; cc < 8; cc += 4) {
    const int kb = cc*32 + kg*8;
    bf16x8 ah = *(const bf16x8*)&Ahi[q & 3][kb];
    bf16x8 al = *(const bf16x8*)&Alo[q & 3][kb];
    union { int i[4]; bf16x8 v; } bh0, bl0, bh1, bl1;
#pragma unroll
    for (int d = 0; d < 4; d++) {
      int k0 = kb + 2*d, k1 = k0 + 1;
      int r0 = ((k0 & 31) << 3) + (k0 >> 5);
      int r1 = ((k1 & 31) << 3) + (k1 >> 5);
      float x0 = w1[r0*EO + q],      x1 = w1[r1*EO + q];
      float y0 = w1[r0*EO + 16 + q], y1 = w1[r1*EO + 16 + q];
      bh0.i[d] = pack_chop2(x0, x1);
      bl0.i[d] = pack_chop2(x0 - chop(x0), x1 - chop(x1));
      bh1.i[d] = pack_chop2(y0, y1);
      bl1.i[d] = pack_chop2(y0 - chop(y0), y1 - chop(y1));
    }
    acc0 = MFMA(ah, bh0.v, acc0); acc0 = MFMA(ah, bl0.v, acc0); acc0 = MFMA(al, bh0.v, acc0);
    acc1 = MFMA(ah, bh1.v, acc1); acc1 = MFMA(ah, bl1.v, acc1); acc1 = MFMA(al, bh1.v, acc1);
  }
  if (lane < 16) {
#pragma unroll
    for (int r = 0; r < 4; r++) { pbuf[w][r][q] = acc0[r]; pbuf[w][r][16+q] = acc1[r]; }
  }
  __syncthreads();
  if (tid < 128) {
    int node = tid >> 5, n = tid & 31;
    float s = pbuf[0][node][n] + pbuf[1][node][n] + pbuf[2][node][n] + pbuf[3][node][n] + b1[n];
    s = lrelu(s);
    h1hi[node][n] = bftrunc(s);
    h1lo[node][n] = bftrunc(s - chop(s));
  }
  __syncthreads();
  {
    bf16x8 ah = *(const bf16x8*)&h1hi[q & 3][kg*8];
    bf16x8 al = *(const bf16x8*)&h1lo[q & 3][kg*8];
    union { int i[4]; bf16x8 v; } bh0, bl0, bh1, bl1;
#pragma unroll
    for (int d = 0; d < 4; d++) {
      int k0 = kg*8 + 2*d, k1 = k0 + 1;
      float x0 = w2[k0*EO + q],      x1 = w2[k1*EO + q];
      float y0 = w2[k0*EO + 16 + q], y1 = w2[k1*EO + 16 + q];
      bh0.i[d] = pack_chop2(x0, x1);
      bl0.i[d] = pack_chop2(x0 - chop(x0), x1 - chop(x1));
      bh1.i[d] = pack_chop2(y0, y1);
      bl1.i[d] = pack_chop2(y0 - chop(y0), y1 - chop(y1));
    }
    f32x4 c0 = {0.f,0.f,0.f,0.f}, c1 = {0.f,0.f,0.f,0.f};
    c0 = MFMA(ah, bh0.v, c0); c0 = MFMA(ah, bl0.v, c0); c0 = MFMA(al, bh0.v, c0);
    c1 = MFMA(ah, bh1.v, c1); c1 = MFMA(ah, bl1.v, c1); c1 = MFMA(al, bh1.v, c1);
    if (lane < 16) {
      float oA = lrelu(c0[w] + b2[q]);
      float oB = lrelu(c1[w] + b2[16+q]);
      e2out[(g*NN+i)*EO + q]      = oA;
      e2out[(g*NN+i)*EO + 16 + q] = oB;
    }
  }
}

// ---------------- Kernel C: BN stats (unchanged) ----------------
__global__ void __launch_bounds__(256) stats_kernel(
    const float* __restrict__ feat0, const float* __restrict__ feat1,
    const float* __restrict__ e1, const float* __restrict__ e2,
    const float* __restrict__ bn_g,
    float* __restrict__ mu_out, float* __restrict__ sg_out)
{
  const int c = blockIdx.x;   // 0..131
  const int tid = threadIdx.x;
  double s1=0, s2=0, q1=0, q2=0;
  for (int t = tid; t < 2*NN; t += 256) {
    int g = t >= NN;
    int i = t - g*NN;
    float val;
    if (c < IN_F)      val = (g ? feat1 : feat0)[i*IN_F + c];
    else if (c < 100)  val = e1[(g*NN+i)*EO + (c-IN_F)];
    else               val = e2[(g*NN+i)*EO + (c-100)];
    double dv = val;
    double wf = (double)(NN-1-i), wsnd = (double)i;
    s1 += wf*dv;  s2 += wsnd*dv;
    double dq = dv*dv;
    q1 += wf*dq;  q2 += wsnd*dq;
  }
#pragma unroll
  for (int off = 32; off >= 1; off >>= 1) {
    s1 += __shfl_xor(s1, off, 64);
    s2 += __shfl_xor(s2, off, 64);
    q1 += __shfl_xor(q1, off, 64);
    q2 += __shfl_xor(q2, off, 64);
  }
  __shared__ double red[4][4];
  const int w = tid >> 6;
  if ((tid & 63) == 0) { red[w][0]=s1; red[w][1]=s2; red[w][2]=q1; red[w][3]=q2; }
  __syncthreads();
  if (tid == 0) {
    double t0 = red[0][0]+red[1][0]+red[2][0]+red[3][0];
    double t1 = red[0][1]+red[1][1]+red[2][1]+red[3][1];
    double t2 = red[0][2]+red[1][2]+red[2][2]+red[3][2];
    double t3 = red[0][3]+red[1][3]+red[2][3]+red[3][3];
    const double M2 = 2.0 * (double)NPAIR;
    double mu1 = t0/M2, mu2 = t1/M2;
    double v1 = t2/M2 - mu1*mu1;
    double v2 = t3/M2 - mu2*mu2;
    mu_out[c]           = (float)mu1;
    mu_out[HALF_FEAT+c] = (float)mu2;
    sg_out[c]           = (float)((double)bn_g[c] / sqrt(v1 + 1e-5));
    sg_out[HALF_FEAT+c] = (float)((double)bn_g[HALF_FEAT+c] / sqrt(v2 + 1e-5));
  }
}

// ---------------- Kernel D: u/v via 16-node block GEMM, sg folded into A ----------------
// u = (x*sg[0:132]) @ W[0:132], v = (x*sg[132:264]) @ W[132:264]. K padded 132->160
// with zero A (B row clamped in-bounds; zero A kills the product).
__global__ void __launch_bounds__(256) uv_kernel(
    const float* __restrict__ feat0, const float* __restrict__ feat1,
    const float* __restrict__ e1, const float* __restrict__ e2,
    const float* __restrict__ sg, const float* __restrict__ mu,
    const float* __restrict__ bn_b,
    const float* __restrict__ lin1_w, const float* __restrict__ lin1_b,
    float* __restrict__ u, float* __restrict__ v, float* __restrict__ c0g)
{
  const int bx = blockIdx.x, g = blockIdx.y;
  const int tid = threadIdx.x;
  if (bx == 48) {              // constant-vector block
    if (g == 0 && tid < EMB) {
      float a0=0.f, a1=0.f, a2=0.f, a3=0.f;
      for (int c = 0; c < FEAT; c += 4) {
        a0 += (bn_b[c+0] - mu[c+0]*sg[c+0]) * lin1_w[(c+0)*EMB + tid];
        a1 += (bn_b[c+1] - mu[c+1]*sg[c+1]) * lin1_w[(c+1)*EMB + tid];
        a2 += (bn_b[c+2] - mu[c+2]*sg[c+2]) * lin1_w[(c+2)*EMB + tid];
        a3 += (bn_b[c+3] - mu[c+3]*sg[c+3]) * lin1_w[(c+3)*EMB + tid];
      }
      c0g[tid] = lin1_b[tid] + ((a0+a1)+(a2+a3));
    }
    return;
  }
  const float* __restrict__ feat = g ? feat1 : feat0;

  __shared__ unsigned short Auh[16][160], Aul[16][160], Avh[16][160], Avl[16][160];
  __shared__ float pbuf[2][4][16][32];

  for (int z = tid; z < 16*33; z += 256) {
    int node = z / 33, part = z - node*33;
    int i = bx*16 + node;
    float4 t; int k;
    if (part < 17)      { t = *(const float4*)(feat + i*IN_F + part*4); k = part*4; }
    else if (part < 25) { t = *(const float4*)(e1 + (g*NN+i)*EO + (part-17)*4); k = IN_F + (part-17)*4; }
    else                { t = *(const float4*)(e2 + (g*NN+i)*EO + (part-25)*4); k = 100 + (part-25)*4; }
    float4 s4 = *(const float4*)(sg + k);
    float4 z4 = *(const float4*)(sg + HALF_FEAT + k);
    float ux=t.x*s4.x, uy=t.y*s4.y, uz=t.z*s4.z, uw=t.w*s4.w;
    float vx=t.x*z4.x, vy=t.y*z4.y, vz=t.z*z4.z, vw=t.w*z4.w;
    u16x4 uh = { bftrunc(ux), bftrunc(uy), bftrunc(uz), bftrunc(uw) };
    u16x4 ul = { bftrunc(ux-chop(ux)), bftrunc(uy-chop(uy)), bftrunc(uz-chop(uz)), bftrunc(uw-chop(uw)) };
    u16x4 vh = { bftrunc(vx), bftrunc(vy), bftrunc(vz), bftrunc(vw) };
    u16x4 vl = { bftrunc(vx-chop(vx)), bftrunc(vy-chop(vy)), bftrunc(vz-chop(vz)), bftrunc(vw-chop(vw)) };
    *(u16x4*)&Auh[node][k] = uh;  *(u16x4*)&Aul[node][k] = ul;
    *(u16x4*)&Avh[node][k] = vh;  *(u16x4*)&Avl[node][k] = vl;
  }
  if (tid < 112) {   // zero-pad k = 132..159
    int node = tid / 7, k = HALF_FEAT + (tid - node*7)*4;
    u16x4 zz = {0,0,0,0};
    *(u16x4*)&Auh[node][k] = zz; *(u16x4*)&Aul[node][k] = zz;
    *(u16x4*)&Avh[node][k] = zz; *(u16x4*)&Avl[node][k] = zz;
  }
  __syncthreads();

  const int lane = tid & 63, w = tid >> 6;
  const int q = lane & 15, kg = lane >> 4;
  f32x4 aU0 = {0.f,0.f,0.f,0.f}, aU1 = {0.f,0.f,0.f,0.f};
  f32x4 aV0 = {0.f,0.f,0.f,0.f}, aV1 = {0.f,0.f,0.f,0.f};
  for (int uu = w; uu < 10; uu += 4) {     // 2 GEMMs x 5 chunks; gm wave-uniform
    int gm = uu / 5, cc = uu - gm*5;
    const unsigned short* Ah = gm ? &Avh[0][0] : &Auh[0][0];
    const unsigned short* Al = gm ? &Avl[0][0] : &Aul[0][0];
    const int kb = cc*32 + kg*8;
    bf16x8 ah = *(const bf16x8*)&Ah[q*160 + kb];
    bf16x8 al = *(const bf16x8*)&Al[q*160 + kb];
    union { int i[4]; bf16x8 v; } bh0, bl0, bh1, bl1;
#pragma unroll
    for (int d = 0; d < 4; d++) {
      int k0 = kb + 2*d, k1 = k0 + 1;
      int r0 = gm ? min(HALF_FEAT + k0, FEAT-1) : k0;
      int r1 = gm ? min(HALF_FEAT + k1, FEAT-1) : k1;
      float x0 = lin1_w[r0*EMB + q],      x1 = lin1_w[r1*EMB + q];
      float y0 = lin1_w[r0*EMB + 16 + q], y1 = lin1_w[r1*EMB + 16 + q];
      bh0.i[d] = pack_chop2(x0, x1);
      bl0.i[d] = pack_chop2(x0 - chop(x0), x1 - chop(x1));
      bh1.i[d] = pack_chop2(y0, y1);
      bl1.i[d] = pack_chop2(y0 - chop(y0), y1 - chop(y1));
    }
    if (gm == 0) {
      aU0 = MFMA(ah, bh0.v, aU0); aU0 = MFMA(ah, bl0.v, aU0); aU0 = MFMA(al, bh0.v, aU0);
      aU1 = MFMA(ah, bh1.v, aU1); aU1 = MFMA(ah, bl1.v, aU1); aU1 = MFMA(al, bh1.v, aU1);
    } else {
      aV0 = MFMA(ah, bh0.v, aV0); aV0 = MFMA(ah, bl0.v, aV0); aV0 = MFMA(al, bh0.v, aV0);
      aV1 = MFMA(ah, bh1.v, aV1); aV1 = MFMA(ah, bl1.v, aV1); aV1 = MFMA(al, bh1.v, aV1);
    }
  }
#pragma unroll
  for (int r = 0; r < 4; r++) {
    pbuf[0][w][kg*4+r][q]    = aU0[r];
    pbuf[0][w][kg*4+r][16+q] = aU1[r];
    pbuf[1][w][kg*4+r][q]    = aV0[r];
    pbuf[1][w][kg*4+r][16+q] = aV1[r];
  }
  __syncthreads();
#pragma unroll
  for (int t = 0; t < 4; t++) {
    int z = tid + 256*t;          // 0..1023
    int gm = z >> 9, rest = z & 511, node = rest >> 5, n = rest & 31;
    float s = pbuf[gm][0][node][n] + pbuf[gm][1][node][n]
            + pbuf[gm][2][node][n] + pbuf[gm][3][node][n];
    float* dst = gm ? v : u;
    dst[(g*NN + bx*16 + node)*EMB + n] = s;
  }
}

// ---------------- Kernel E: pair MLP, MFMA + shfl-butterfly epilogue ----------------
__global__ void __launch_bounds__(256) pair_kernel(
    const float* __restrict__ u, const float* __restrict__ v,
    const float* __restrict__ c0g,
    const float* __restrict__ lin2_w, const float* __restrict__ lin2_b,
    const float* __restrict__ lin3_w, const float* __restrict__ lin3_b,
    float2* __restrict__ out)
{
  const int g = blockIdx.y;
  int rem = blockIdx.x;        // 0..1175 triangular tile id
  int a = 0;
  while (rem >= 48 - a) { rem -= 48 - a; a++; }
  const int b = a + rem;

  __shared__ float su[16*36], sv[16*36];
  const int tid = threadIdx.x;
  {
    int r = tid >> 5, c = tid & 31;
    su[r*36+c] = u[(g*NN + a*16 + r)*EMB + c];
    sv[r*36+c] = v[(g*NN + b*16 + r)*EMB + c];
    r += 8;
    su[r*36+c] = u[(g*NN + a*16 + r)*EMB + c];
    sv[r*36+c] = v[(g*NN + b*16 + r)*EMB + c];
  }
  __syncthreads();

  const int lane = tid & 63, w = tid >> 6;
  const int q = lane & 15, kg = lane >> 4;

  union { int i[4]; bf16x8 v; } whi0, wlo0, whi1, wlo1;
#pragma unroll
  for (int d = 0; d < 4; d++) {
    float w0a = lin2_w[(kg*8+2*d)*32 + q],      w0b = lin2_w[(kg*8+2*d+1)*32 + q];
    float w1a = lin2_w[(kg*8+2*d)*32 + 16 + q], w1b = lin2_w[(kg*8+2*d+1)*32 + 16 + q];
    whi0.i[d] = pack_chop2(w0a, w0b);
    wlo0.i[d] = pack_chop2(w0a - chop(w0a), w0b - chop(w0b));
    whi1.i[d] = pack_chop2(w1a, w1b);
    wlo1.i[d] = pack_chop2(w1a - chop(w1a), w1b - chop(w1b));
  }
  float svc[8];
#pragma unroll
  for (int jj = 0; jj < 8; jj++)
    svc[jj] = sv[q*36 + kg*8 + jj] + c0g[kg*8+jj];
  // epilogue per-lane constants: this lane's two h2 columns are q and 16+q
  const float b2a = lin2_b[q], b2b = lin2_b[16+q];
  const float2 w3a = ((const float2*)lin3_w)[q];
  const float2 w3b = ((const float2*)lin3_w)[16+q];
  const float b30 = lin3_b[0], b31 = lin3_b[1];

#pragma unroll
  for (int t = 0; t < 4; t++) {
    const int ty = w*4 + t;
    const float4 sa = *(const float4*)&su[ty*36 + kg*8];
    const float4 sb = *(const float4*)&su[ty*36 + kg*8 + 4];
    float se[8] = {sa.x, sa.y, sa.z, sa.w, sb.x, sb.y, sb.z, sb.w};
    union { int i[4]; bf16x8 v; } ahi, alo;
#pragma unroll
    for (int d = 0; d < 4; d++) {
      float s0 = se[2*d]   + svc[2*d];
      float s1 = se[2*d+1] + svc[2*d+1];
      s0 = lrelu(s0); s1 = lrelu(s1);
      ahi.i[d] = pack_chop2(s0, s1);
      alo.i[d] = pack_chop2(s0 - chop(s0), s1 - chop(s1));
    }
    f32x4 acc0 = {0.f,0.f,0.f,0.f}, acc1 = {0.f,0.f,0.f,0.f};
    acc0 = MFMA(ahi.v, whi0.v, acc0); acc1 = MFMA(ahi.v, whi1.v, acc1);
    acc0 = MFMA(ahi.v, wlo0.v, acc0); acc1 = MFMA(ahi.v, wlo1.v, acc1);
    acc0 = MFMA(alo.v, whi0.v, acc0); acc1 = MFMA(alo.v, whi1.v, acc1);
    // lane holds h2[row kg*4+r][col q] (acc0) and [col 16+q] (acc1):
    // fold lin3 per-lane, then 16-lane butterfly sums over columns.
    float p0[4], p1[4];
#pragma unroll
    for (int r = 0; r < 4; r++) {
      float hA = lrelu(acc0[r] + b2a);
      float hB = lrelu(acc1[r] + b2b);
      p0[r] = hA*w3a.x + hB*w3b.x;
      p1[r] = hA*w3a.y + hB*w3b.y;
    }
#pragma unroll
    for (int s = 1; s <= 8; s <<= 1) {
#pragma unroll
      for (int r = 0; r < 4; r++) {
        p0[r] += __shfl_xor(p0[r], s, 64);
        p1[r] += __shfl_xor(p1[r], s, 64);
      }
    }
    const int i = a*16 + ty;
    if (q < 4) {
      const int m = kg*4 + q;        // this lane writes row m of the tile
      const int j = b*16 + m;
      if (j > i) {
        long p = (long)i*NN - (long)i*(i+1)/2 + (j - i - 1);
        out[(long)g*NPAIR + p] = make_float2(p0[q] + b30, p1[q] + b31);
      }
    }
  }
}

extern "C" void kernel_launch(void* const* d_in, const int* in_sizes, int n_in,
                              void* d_out, int out_size, void* d_ws, size_t ws_size,
                              hipStream_t stream)
{
  const float* feat0  = (const float*)d_in[0];
  const float* feat1  = (const float*)d_in[1];
  const float* ec1_w1 = (const float*)d_in[2];
  const float* ec1_b1 = (const float*)d_in[3];
  const float* ec1_w2 = (const float*)d_in[4];
  const float* ec1_b2 = (const float*)d_in[5];
  const float* ec2_w1 = (const float*)d_in[6];
  const float* ec2_b1 = (const float*)d_in[7];
  const float* ec2_w2 = (const float*)d_in[8];
  const float* ec2_b2 = (const float*)d_in[9];
  const float* bn_g   = (const float*)d_in[10];
  const float* bn_b   = (const float*)d_in[11];
  const float* lin1_w = (const float*)d_in[12];
  const float* lin1_b = (const float*)d_in[13];
  const float* lin2_w = (const float*)d_in[14];
  const float* lin2_b = (const float*)d_in[15];
  const float* lin3_w = (const float*)d_in[16];
  const float* lin3_b = (const float*)d_in[17];

  char* ws = (char*)d_ws;
  int*   idx = (int*)  (ws + 0);
  float* e1  = (float*)(ws + 49152);
  float* e2  = (float*)(ws + 245760);
  float* u   = (float*)(ws + 442368);
  float* v   = (float*)(ws + 638976);
  float* mu  = (float*)(ws + 835584);
  float* sg  = (float*)(ws + 836640);
  float* c0g = (float*)(ws + 837696);

  topk_ec1_kernel<<<dim3(192,2), 256, 0, stream>>>(feat0, feat1, ec1_w1, ec1_b1,
                                                   ec1_w2, ec1_b2, idx, e1);
  ec2_kernel<<<dim3(192,2), 256, 0, stream>>>(idx, e1, ec2_w1, ec2_b1,
                                              ec2_w2, ec2_b2, e2);
  stats_kernel<<<dim3(132), 256, 0, stream>>>(feat0, feat1, e1, e2, bn_g, mu, sg);
  uv_kernel<<<dim3(49,2), 256, 0, stream>>>(feat0, feat1, e1, e2, sg, mu, bn_b,
                                            lin1_w, lin1_b, u, v, c0g);
  pair_kernel<<<dim3(1176,2), 256, 0, stream>>>(u, v, c0g, lin2_w, lin2_b,
                                                lin3_w, lin3_b, (float2*)d_out);
}

// Round 6
// 135.347 us; speedup vs baseline: 1.0397x; 1.0397x over previous
//
#include <hip/hip_runtime.h>

#define NN 768
#define IN_F 68
#define KNN 8
#define EO 32
#define FEAT 264
#define HALF_FEAT 132
#define EMB 32
#define NPAIR 294528   // 768*767/2

typedef __attribute__((ext_vector_type(8))) short bf16x8;
typedef __attribute__((ext_vector_type(4))) float f32x4;

// pack hi16(x1):hi16(x0) into one dword — bf16 truncation of two floats, 1 v_perm
static __device__ __forceinline__ int pack_chop2(float x0, float x1) {
  return __builtin_amdgcn_perm(__float_as_uint(x1), __float_as_uint(x0), 0x07060302);
}
static __device__ __forceinline__ float chop(float x) {
  return __uint_as_float(__float_as_uint(x) & 0xffff0000u);
}

// ---------------- Kernel A: top-8 neighbors (stable, jax top_k semantics) + EdgeConv1 ----
__global__ void __launch_bounds__(64) topk_ec1_kernel(
    const float* __restrict__ feat0, const float* __restrict__ feat1,
    const float* __restrict__ w1, const float* __restrict__ b1,
    const float* __restrict__ w2, const float* __restrict__ b2,
    int* __restrict__ idx_out, float* __restrict__ e1out)
{
  const int i = blockIdx.x, g = blockIdx.y;
  const float* __restrict__ feat = g ? feat1 : feat0;
  const int lane = threadIdx.x;

  __shared__ unsigned long long keys[64*8];
  __shared__ int nbr[8];
  __shared__ float gl[KNN*IN_F];
  __shared__ float hsh[EO];

  const float4 ci = *(const float4*)(feat + i*IN_F);

  float4 cand[12];
#pragma unroll
  for (int t = 0; t < 12; t++)
    cand[t] = *(const float4*)(feat + (lane + 64*t)*IN_F);

  float bd[8]; int bidx[8];
#pragma unroll
  for (int k = 0; k < 8; k++) { bd[k] = 1e30f; bidx[k] = 0; }
#pragma unroll
  for (int t = 0; t < 12; t++) {
    const int j = lane + 64*t;
    float d = fabsf(ci.x - cand[t].x);   // same sequential add order as ref sum(-1)
    d += fabsf(ci.y - cand[t].y);
    d += fabsf(ci.z - cand[t].z);
    d += fabsf(ci.w - cand[t].w);
    if (d < bd[7]) {
#pragma unroll
      for (int k = 7; k >= 1; k--) {
        if (d < bd[k-1])    { bd[k] = bd[k-1]; bidx[k] = bidx[k-1]; }
        else if (d < bd[k]) { bd[k] = d;       bidx[k] = j; }
      }
      if (d < bd[0]) { bd[0] = d; bidx[0] = j; }
    }
  }
#pragma unroll
  for (int k = 0; k < 8; k++)
    keys[lane*8+k] = ((unsigned long long)__float_as_uint(bd[k]) << 32) | (unsigned)bidx[k];
  __syncthreads();
  int pos = 0;
#pragma unroll
  for (int r = 0; r < 8; r++) {
    unsigned long long mykey = keys[lane*8 + pos];
    unsigned long long mn = mykey;
#pragma unroll
    for (int s = 32; s >= 1; s >>= 1) {
      unsigned long long o = __shfl_xor(mn, s, 64);
      mn = (o < mn) ? o : mn;
    }
    if (mykey == mn) pos++;
    if (lane == 0) {
      int nb = (int)(mn & 0xffffffffull);
      nbr[r] = nb;
      idx_out[(g*NN+i)*8 + r] = nb;
    }
  }
  __syncthreads();

  for (int z = lane; z < KNN*17; z += 64) {
    int k = z / 17, q = z - k*17;
    *(float4*)&gl[k*IN_F + q*4] = *(const float4*)(feat + nbr[k]*IN_F + q*4);
  }
  __syncthreads();

  // layer1, 8 independent accumulator chains (k-major) for ILP
  const int e = lane & 31, hf = lane >> 5;
  float ak[8];
#pragma unroll
  for (int k = 0; k < 8; k++) ak[k] = 0.f;
  const int cbeg = hf*34;
  for (int c = cbeg; c < cbeg+34; c++) {
#pragma unroll
    for (int k = 0; k < 8; k++)
      ak[k] += gl[k*IN_F+c] * w1[(c*8+k)*EO + e];
  }
  float acc = ((ak[0]+ak[1])+(ak[2]+ak[3])) + ((ak[4]+ak[5])+(ak[6]+ak[7]));
  acc += __shfl_xor(acc, 32, 64);
  if (hf == 0) {
    float h = acc + b1[e];
    hsh[e] = fmaxf(h, 0.01f*h);
  }
  __syncthreads();
  if (lane < 32) {
    float o0=0.f, o1=0.f, o2=0.f, o3=0.f;
#pragma unroll
    for (int m = 0; m < 32; m += 4) {
      o0 += hsh[m+0] * w2[(m+0)*EO + lane];
      o1 += hsh[m+1] * w2[(m+1)*EO + lane];
      o2 += hsh[m+2] * w2[(m+2)*EO + lane];
      o3 += hsh[m+3] * w2[(m+3)*EO + lane];
    }
    float o = b2[lane] + ((o0+o1)+(o2+o3));
    o = fmaxf(o, 0.01f*o);
    e1out[(g*NN+i)*EO + lane] = o;
  }
}

// ---------------- Kernel B: EdgeConv2 ----------------
__global__ void __launch_bounds__(64) ec2_kernel(
    const int* __restrict__ idx, const float* __restrict__ e1,
    const float* __restrict__ w1, const float* __restrict__ b1,
    const float* __restrict__ w2, const float* __restrict__ b2,
    float* __restrict__ e2out)
{
  const int i = blockIdx.x, g = blockIdx.y;
  const int lane = threadIdx.x;
  __shared__ float gl[KNN*EO];
  __shared__ float hsh[EO];
  {
    const int k = lane >> 3, q = lane & 7;
    const int nb = idx[(g*NN+i)*8 + k];
    *(float4*)&gl[k*EO + q*4] = *(const float4*)(e1 + (g*NN+nb)*EO + q*4);
  }
  __syncthreads();
  const int e = lane & 31, hf = lane >> 5;
  float ak[8];
#pragma unroll
  for (int k = 0; k < 8; k++) ak[k] = 0.f;
  const int cbeg = hf*16;
  for (int c = cbeg; c < cbeg+16; c++) {
#pragma unroll
    for (int k = 0; k < 8; k++)
      ak[k] += gl[k*EO+c] * w1[(c*8+k)*EO + e];
  }
  float acc = ((ak[0]+ak[1])+(ak[2]+ak[3])) + ((ak[4]+ak[5])+(ak[6]+ak[7]));
  acc += __shfl_xor(acc, 32, 64);
  if (hf == 0) {
    float h = acc + b1[e];
    hsh[e] = fmaxf(h, 0.01f*h);
  }
  __syncthreads();
  if (lane < 32) {
    float o0=0.f, o1=0.f, o2=0.f, o3=0.f;
#pragma unroll
    for (int m = 0; m < 32; m += 4) {
      o0 += hsh[m+0] * w2[(m+0)*EO + lane];
      o1 += hsh[m+1] * w2[(m+1)*EO + lane];
      o2 += hsh[m+2] * w2[(m+2)*EO + lane];
      o3 += hsh[m+3] * w2[(m+3)*EO + lane];
    }
    float o = b2[lane] + ((o0+o1)+(o2+o3));
    o = fmaxf(o, 0.01f*o);
    e2out[(g*NN+i)*EO + lane] = o;
  }
}

// ---------------- Kernel C: BN stats (weighted node sums, shfl reduce) ----------------
__global__ void __launch_bounds__(256) stats_kernel(
    const float* __restrict__ feat0, const float* __restrict__ feat1,
    const float* __restrict__ e1, const float* __restrict__ e2,
    const float* __restrict__ bn_g,
    float* __restrict__ mu_out, float* __restrict__ sg_out)
{
  const int c = blockIdx.x;   // 0..131
  const int tid = threadIdx.x;
  double s1=0, s2=0, q1=0, q2=0;
  for (int t = tid; t < 2*NN; t += 256) {
    int g = t >= NN;
    int i = t - g*NN;
    float val;
    if (c < IN_F)      val = (g ? feat1 : feat0)[i*IN_F + c];
    else if (c < 100)  val = e1[(g*NN+i)*EO + (c-IN_F)];
    else               val = e2[(g*NN+i)*EO + (c-100)];
    double dv = val;
    double wf = (double)(NN-1-i), wsnd = (double)i;
    s1 += wf*dv;  s2 += wsnd*dv;
    double dq = dv*dv;
    q1 += wf*dq;  q2 += wsnd*dq;
  }
#pragma unroll
  for (int off = 32; off >= 1; off >>= 1) {
    s1 += __shfl_xor(s1, off, 64);
    s2 += __shfl_xor(s2, off, 64);
    q1 += __shfl_xor(q1, off, 64);
    q2 += __shfl_xor(q2, off, 64);
  }
  __shared__ double red[4][4];
  const int w = tid >> 6;
  if ((tid & 63) == 0) { red[w][0]=s1; red[w][1]=s2; red[w][2]=q1; red[w][3]=q2; }
  __syncthreads();
  if (tid == 0) {
    double t0 = red[0][0]+red[1][0]+red[2][0]+red[3][0];
    double t1 = red[0][1]+red[1][1]+red[2][1]+red[3][1];
    double t2 = red[0][2]+red[1][2]+red[2][2]+red[3][2];
    double t3 = red[0][3]+red[1][3]+red[2][3]+red[3][3];
    const double M2 = 2.0 * (double)NPAIR;
    double mu1 = t0/M2, mu2 = t1/M2;
    double v1 = t2/M2 - mu1*mu1;
    double v2 = t3/M2 - mu2*mu2;
    mu_out[c]           = (float)mu1;
    mu_out[HALF_FEAT+c] = (float)mu2;
    sg_out[c]           = (float)((double)bn_g[c] / sqrt(v1 + 1e-5));
    sg_out[HALF_FEAT+c] = (float)((double)bn_g[HALF_FEAT+c] / sqrt(v2 + 1e-5));
  }
}

// ---------------- Kernel D: per-node u/v, plus c0 ----------------
__global__ void __launch_bounds__(64) uv_c0_kernel(
    const float* __restrict__ feat0, const float* __restrict__ feat1,
    const float* __restrict__ e1, const float* __restrict__ e2,
    const float* __restrict__ sg, const float* __restrict__ mu,
    const float* __restrict__ bn_b,
    const float* __restrict__ lin1_w, const float* __restrict__ lin1_b,
    float* __restrict__ u, float* __restrict__ v, float* __restrict__ c0g)
{
  const int i = blockIdx.x, g = blockIdx.y;
  const int t = threadIdx.x;
  if (i == NN) {
    if (g == 0 && t < EMB) {
      float a0=0.f, a1=0.f, a2=0.f, a3=0.f;
      for (int c = 0; c < FEAT; c += 4) {
        a0 += (bn_b[c+0] - mu[c+0]*sg[c+0]) * lin1_w[(c+0)*EMB + t];
        a1 += (bn_b[c+1] - mu[c+1]*sg[c+1]) * lin1_w[(c+1)*EMB + t];
        a2 += (bn_b[c+2] - mu[c+2]*sg[c+2]) * lin1_w[(c+2)*EMB + t];
        a3 += (bn_b[c+3] - mu[c+3]*sg[c+3]) * lin1_w[(c+3)*EMB + t];
      }
      c0g[t] = lin1_b[t] + ((a0+a1)+(a2+a3));
    }
    return;
  }
  __shared__ float x[HALF_FEAT];
  for (int c = t; c < IN_F; c += 64) x[c] = (g ? feat1 : feat0)[i*IN_F + c];
  if (t < 32) x[IN_F + t]     = e1[(g*NN+i)*EO + t];
  else        x[100 + (t-32)] = e2[(g*NN+i)*EO + (t-32)];
  __syncthreads();
  const int e = t & 31, hf = t >> 5;
  const int base = hf * HALF_FEAT;
  float a0=0.f, a1=0.f, a2=0.f, a3=0.f;
  for (int c = 0; c < HALF_FEAT; c += 4) {
    a0 += x[c+0] * sg[base+c+0] * lin1_w[(base+c+0)*EMB + e];
    a1 += x[c+1] * sg[base+c+1] * lin1_w[(base+c+1)*EMB + e];
    a2 += x[c+2] * sg[base+c+2] * lin1_w[(base+c+2)*EMB + e];
    a3 += x[c+3] * sg[base+c+3] * lin1_w[(base+c+3)*EMB + e];
  }
  float acc = ((a0+a1)+(a2+a3));
  float* dst = hf ? v : u;
  dst[(g*NN+i)*EMB + e] = acc;
}

// ---------------- Kernel E: pair MLP via split-bf16 MFMA ----------------
// Split = truncate-to-bf16 + exact fp32 residual (chop is exact; residual is a
// same-exponent subtract -> exact). Dropped terms ~2^-16 relative. Packing two
// hi-halves per dword is a single v_perm_b32.
__global__ void __launch_bounds__(256) pair_kernel(
    const float* __restrict__ u, const float* __restrict__ v,
    const float* __restrict__ c0g,
    const float* __restrict__ lin2_w, const float* __restrict__ lin2_b,
    const float* __restrict__ lin3_w, const float* __restrict__ lin3_b,
    float2* __restrict__ out)
{
  const int g = blockIdx.y;
  int rem = blockIdx.x;        // 0..1175 triangular tile id
  int a = 0;
  while (rem >= 48 - a) { rem -= 48 - a; a++; }
  const int b = a + rem;

  __shared__ float su[16*36], sv[16*36];
  __shared__ float wbuf[4][16*36];
  const int tid = threadIdx.x;
  {
    int r = tid >> 5, c = tid & 31;
    su[r*36+c] = u[(g*NN + a*16 + r)*EMB + c];
    sv[r*36+c] = v[(g*NN + b*16 + r)*EMB + c];
    r += 8;
    su[r*36+c] = u[(g*NN + a*16 + r)*EMB + c];
    sv[r*36+c] = v[(g*NN + b*16 + r)*EMB + c];
  }
  __syncthreads();

  const int lane = tid & 63, w = tid >> 6;
  const int q = lane & 15, kg = lane >> 4;   // q: m/n index, kg: k-group

  // W2 fragments (B operand: n = lane&15, k = kg*8+jj), chop/residual split
  union { int i[4]; bf16x8 v; } whi0, wlo0, whi1, wlo1;
#pragma unroll
  for (int d = 0; d < 4; d++) {
    float w0a = lin2_w[(kg*8+2*d)*32 + q],      w0b = lin2_w[(kg*8+2*d+1)*32 + q];
    float w1a = lin2_w[(kg*8+2*d)*32 + 16 + q], w1b = lin2_w[(kg*8+2*d+1)*32 + 16 + q];
    whi0.i[d] = pack_chop2(w0a, w0b);
    wlo0.i[d] = pack_chop2(w0a - chop(w0a), w0b - chop(w0b));
    whi1.i[d] = pack_chop2(w1a, w1b);
    wlo1.i[d] = pack_chop2(w1a - chop(w1a), w1b - chop(w1b));
  }
  // sv + c0 for this lane's (m=q, k=kg*8+jj) — tile-invariant
  float svc[8];
#pragma unroll
  for (int jj = 0; jj < 8; jj++)
    svc[jj] = sv[q*36 + kg*8 + jj] + c0g[kg*8+jj];
  // epilogue constants for this lane's n-range
  float2 w3v[8]; float b2v[8];
#pragma unroll
  for (int jj = 0; jj < 8; jj++) {
    w3v[jj] = ((const float2*)lin3_w)[kg*8+jj];
    b2v[jj] = lin2_b[kg*8+jj];
  }
  const float b30 = lin3_b[0], b31 = lin3_b[1];

  float* wb = wbuf[w];
#pragma unroll
  for (int t = 0; t < 4; t++) {
    const int ty = w*4 + t;
    // A fragment: rows m = 16 j-nodes, k = embedding dim; chop/residual split
    const float4 sa = *(const float4*)&su[ty*36 + kg*8];
    const float4 sb = *(const float4*)&su[ty*36 + kg*8 + 4];
    float se[8] = {sa.x, sa.y, sa.z, sa.w, sb.x, sb.y, sb.z, sb.w};
    union { int i[4]; bf16x8 v; } ahi, alo;
#pragma unroll
    for (int d = 0; d < 4; d++) {
      float s0 = se[2*d]   + svc[2*d];
      float s1 = se[2*d+1] + svc[2*d+1];
      s0 = fmaxf(s0, 0.01f*s0);
      s1 = fmaxf(s1, 0.01f*s1);
      ahi.i[d] = pack_chop2(s0, s1);
      alo.i[d] = pack_chop2(s0 - chop(s0), s1 - chop(s1));
    }
    f32x4 acc0 = {0.f,0.f,0.f,0.f}, acc1 = {0.f,0.f,0.f,0.f};
    acc0 = __builtin_amdgcn_mfma_f32_16x16x32_bf16(ahi.v, whi0.v, acc0, 0,0,0);
    acc1 = __builtin_amdgcn_mfma_f32_16x16x32_bf16(ahi.v, whi1.v, acc1, 0,0,0);
    acc0 = __builtin_amdgcn_mfma_f32_16x16x32_bf16(ahi.v, wlo0.v, acc0, 0,0,0);
    acc1 = __builtin_amdgcn_mfma_f32_16x16x32_bf16(ahi.v, wlo1.v, acc1, 0,0,0);
    acc0 = __builtin_amdgcn_mfma_f32_16x16x32_bf16(alo.v, whi0.v, acc0, 0,0,0);
    acc1 = __builtin_amdgcn_mfma_f32_16x16x32_bf16(alo.v, whi1.v, acc1, 0,0,0);
    // D layout: row m = kg*4+r, col n = q (acc0: n<16, acc1: n>=16)
#pragma unroll
    for (int r = 0; r < 4; r++) {
      wb[(kg*4+r)*36 + q]      = acc0[r];
      wb[(kg*4+r)*36 + 16 + q] = acc1[r];
    }
    // epilogue: lane handles pair m=q, n-range kg*8..kg*8+8
    float o0 = 0.f, o1 = 0.f;
#pragma unroll
    for (int jj = 0; jj < 8; jj++) {
      float h = wb[q*36 + kg*8 + jj] + b2v[jj];
      h = fmaxf(h, 0.01f*h);
      o0 += h * w3v[jj].x;
      o1 += h * w3v[jj].y;
    }
    o0 += __shfl_xor(o0, 16, 64); o0 += __shfl_xor(o0, 32, 64);
    o1 += __shfl_xor(o1, 16, 64); o1 += __shfl_xor(o1, 32, 64);
    const int i = a*16 + ty, j = b*16 + q;
    if (lane < 16 && j > i) {
      long p = (long)i*NN - (long)i*(i+1)/2 + (j - i - 1);
      out[(long)g*NPAIR + p] = make_float2(o0 + b30, o1 + b31);
    }
  }
}

extern "C" void kernel_launch(void* const* d_in, const int* in_sizes, int n_in,
                              void* d_out, int out_size, void* d_ws, size_t ws_size,
                              hipStream_t stream)
{
  const float* feat0  = (const float*)d_in[0];
  const float* feat1  = (const float*)d_in[1];
  const float* ec1_w1 = (const float*)d_in[2];
  const float* ec1_b1 = (const float*)d_in[3];
  const float* ec1_w2 = (const float*)d_in[4];
  const float* ec1_b2 = (const float*)d_in[5];
  const float* ec2_w1 = (const float*)d_in[6];
  const float* ec2_b1 = (const float*)d_in[7];
  const float* ec2_w2 = (const float*)d_in[8];
  const float* ec2_b2 = (const float*)d_in[9];
  const float* bn_g   = (const float*)d_in[10];
  const float* bn_b   = (const float*)d_in[11];
  const float* lin1_w = (const float*)d_in[12];
  const float* lin1_b = (const float*)d_in[13];
  const float* lin2_w = (const float*)d_in[14];
  const float* lin2_b = (const float*)d_in[15];
  const float* lin3_w = (const float*)d_in[16];
  const float* lin3_b = (const float*)d_in[17];

  char* ws = (char*)d_ws;
  int*   idx = (int*)  (ws + 0);
  float* e1  = (float*)(ws + 49152);
  float* e2  = (float*)(ws + 245760);
  float* u   = (float*)(ws + 442368);
  float* v   = (float*)(ws + 638976);
  float* mu  = (float*)(ws + 835584);
  float* sg  = (float*)(ws + 836640);
  float* c0g = (float*)(ws + 837696);

  topk_ec1_kernel<<<dim3(768,2), 64, 0, stream>>>(feat0, feat1, ec1_w1, ec1_b1,
                                                  ec1_w2, ec1_b2, idx, e1);
  ec2_kernel<<<dim3(768,2), 64, 0, stream>>>(idx, e1, ec2_w1, ec2_b1,
                                             ec2_w2, ec2_b2, e2);
  stats_kernel<<<dim3(132), 256, 0, stream>>>(feat0, feat1, e1, e2, bn_g, mu, sg);
  uv_c0_kernel<<<dim3(769,2), 64, 0, stream>>>(feat0, feat1, e1, e2, sg, mu, bn_b,
                                               lin1_w, lin1_b, u, v, c0g);
  pair_kernel<<<dim3(1176,2), 256, 0, stream>>>(u, v, c0g, lin2_w, lin2_b,
                                                lin3_w, lin3_b, (float2*)d_out);
}